// Round 3
// baseline (123.320 us; speedup 1.0000x reference)
//
#include <hip/hip_runtime.h>

#define N 8192
#define D 256

typedef short short8 __attribute__((ext_vector_type(8)));
typedef float f32x4 __attribute__((ext_vector_type(4)));

__device__ __forceinline__ unsigned short f2bf(float f) {
    unsigned int u = __float_as_uint(f);
    u += 0x7fffu + ((u >> 16) & 1u);   // RNE
    return (unsigned short)(u >> 16);
}
__device__ __forceinline__ float bf2f(unsigned short h) {
    return __uint_as_float(((unsigned int)h) << 16);
}

// Kernel 0 (R15 version, unchanged): fp32 -> bf16 into FRAGMENT-MAJOR xb2:
// 16B chunk ((row>>4)*8 + kk)*64 + lane holds
// X[(row>>4)*16 + (lane&15)][kk*32 + (lane>>4)*8 .. +8) as bf16.
// One wave per 16-row group, grid 512 x 64 -> all 256 CUs active.
// Also row squared norms + zero S/L accumulators.
__global__ __launch_bounds__(64) void k_cvt(const float* __restrict__ x,
                                            unsigned short* __restrict__ xb2,
                                            float* __restrict__ sq,
                                            float* __restrict__ Sarr,
                                            float* __restrict__ Larr) {
    const int lane = threadIdx.x & 63;
    const int c = lane & 15, q8 = lane >> 4;
    const int grp = blockIdx.x;               // 16-row group
    const int row = grp * 16 + c;

    float ssum = 0.0f;
#pragma unroll
    for (int kk = 0; kk < 8; ++kk) {
        const float4* gp = (const float4*)(x + (size_t)row * D + kk * 32 + q8 * 8);
        float4 v0 = gp[0], v1 = gp[1];
        unsigned short h[8];
        h[0] = f2bf(v0.x); h[1] = f2bf(v0.y); h[2] = f2bf(v0.z); h[3] = f2bf(v0.w);
        h[4] = f2bf(v1.x); h[5] = f2bf(v1.y); h[6] = f2bf(v1.z); h[7] = f2bf(v1.w);
        short8 p;
#pragma unroll
        for (int i = 0; i < 8; ++i) {
            float f = bf2f(h[i]);
            ssum = fmaf(f, f, ssum);
            p[i] = (short)h[i];
        }
        ((short8*)xb2)[(grp * 8 + kk) * 64 + lane] = p;
    }
    ssum += __shfl_xor(ssum, 16, 64);
    ssum += __shfl_xor(ssum, 32, 64);
    if (q8 == 0) {
        sq[row] = ssum;
        Sarr[row] = 0.0f;
        Larr[row] = 0.0f;
    }
}

// Kernel 1 (R17: DIRECT-L2 B-path). Post-mortem of R13/R16: two different
// schedules (2-barrier and 8-phase) both pin at ~40 us, insensitive to
// occupancy/conflicts/pipelining/work-halving -> the LDS+barrier structure
// itself is the cost, not the schedule. xb2 is 4 MB (= one XCD's L2, L3
// trivially) and is ALREADY stored in the exact fragment-major order the
// MFMA consumes, so the GLDS16->LDS->ds_read round trip is a verbatim
// copy (guide common-mistake #7: don't stage L2-fit data). This version
// deletes LDS, barriers, and phases entirely: each wave streams its
// B-fragments straight from L2 with coalesced 1KB global_load_dwordx4
// and relies on 8 waves/CU of TLP to keep the MFMA pipe fed (3.5x
// oversubscribed). A-fragments, screen, C/D mapping, reduction, atomics
// are byte-identical to the verified R13/R16 kernels.
__global__ __launch_bounds__(256, 2) void k_gram(const unsigned short* __restrict__ xb2,
                                                 const float* __restrict__ sq,
                                                 const float* __restrict__ temp,
                                                 float* __restrict__ Sarr,
                                                 float* __restrict__ Larr) {
    const int tid = threadIdx.x;
    const int wv = tid >> 6, lane = tid & 63;
    const int q8 = lane >> 4, c = lane & 15;
    const int rowbase = blockIdx.x * 256;
    const int ybase = blockIdx.y * 512;
    const float T = temp[0];
    const float LOG2E = 1.44269504f;
    const float s2 = -LOG2E / (2.0f * T * T);   // log2-scaled; t2 = c2*g + ar + bc
    const float c2 = -2.0f * s2;

    // A fragments: wave wv owns rows rowbase + wv*64 .. +63 (coalesced)
    short8 av[4][8];
#pragma unroll
    for (int tr = 0; tr < 4; ++tr) {
        const int grp = (rowbase >> 4) + wv * 4 + tr;
#pragma unroll
        for (int kk = 0; kk < 8; ++kk)
            av[tr][kk] = ((const short8*)xb2)[(grp * 8 + kk) * 64 + lane];
    }
    float ar[16];   // sq[row] * s2 (negative)
#pragma unroll
    for (int tr = 0; tr < 4; ++tr)
#pragma unroll
        for (int r = 0; r < 4; ++r)
            ar[tr * 4 + r] = sq[rowbase + wv * 64 + tr * 16 + q8 * 4 + r] * s2;
    float armax = ar[0];
#pragma unroll
    for (int k = 1; k < 16; ++k) armax = fmaxf(armax, ar[k]);

    float Sr[16], Mr[16];
#pragma unroll
    for (int k = 0; k < 16; ++k) { Sr[k] = 0.f; Mr[k] = 0.f; }

    // 512 columns per block = 32 16-col fragment groups, streamed from L2.
    // bv[kk] here receives EXACTLY the bytes the old LDS path delivered:
    // Bs read (tc*8+kk)*512 + lane*8 == xb2[((grp*8)+kk)*64 + lane].
    for (int ct = 0; ct < 32; ++ct) {
        const int colbase = ybase + ct * 16;
        const int grp = colbase >> 4;
        const short8* bp = (const short8*)xb2 + (size_t)grp * 8 * 64;

        short8 bv[8];
#pragma unroll
        for (int kk = 0; kk < 8; ++kk)
            bv[kk] = bp[kk * 64 + lane];

        const float bc = sq[colbase + c] * s2;

        f32x4 acc[4];
#pragma unroll
        for (int tr = 0; tr < 4; ++tr)
#pragma unroll
            for (int r = 0; r < 4; ++r) acc[tr][r] = 0.0f;

#pragma unroll
        for (int kk = 0; kk < 8; ++kk)
#pragma unroll
            for (int tr = 0; tr < 4; ++tr)
                acc[tr] = __builtin_amdgcn_mfma_f32_16x16x32_bf16(
                    av[tr][kk], bv[kk], acc[tr], 0, 0, 0);

        // screen: conservative upper bound on t2 over this lane's 16 elems
        float gmax = acc[0][0];
#pragma unroll
        for (int tr = 0; tr < 4; ++tr)
#pragma unroll
            for (int r = 0; r < 4; ++r) gmax = fmaxf(gmax, acc[tr][r]);
        const float bound = fmaf(gmax, c2, armax + bc);

        if (__any(bound >= -115.0f)) {
            // exact slow path (diagonal-touching subtiles, ~1%)
#pragma unroll
            for (int tr = 0; tr < 4; ++tr)
#pragma unroll
                for (int r = 0; r < 4; ++r) {
                    float g = acc[tr][r];
                    float t2 = fminf(fmaf(g, c2, ar[tr * 4 + r] + bc), 0.0f);
                    float e = __builtin_amdgcn_exp2f(t2);
                    Sr[tr * 4 + r] += e;
                    Mr[tr * 4 + r] = fmaf(e, t2, Mr[tr * 4 + r]);
                }
        }
        // else: all values underflow fp32 -> contribute exactly 0
    }

    // row-sum commit: reduce across the 16 col-lanes (lane bits 0..3)
#pragma unroll
    for (int m = 1; m <= 8; m <<= 1)
#pragma unroll
        for (int k = 0; k < 16; ++k) {
            Sr[k] += __shfl_xor(Sr[k], m, 64);
            Mr[k] += __shfl_xor(Mr[k], m, 64);
        }
    if (c == 0) {
        const float LN2 = 0.69314718f;   // Mr holds sum e*log2(k); rescale to ln
#pragma unroll
        for (int k = 0; k < 16; ++k) {
            int row = rowbase + wv * 64 + (k >> 2) * 16 + q8 * 4 + (k & 3);
            atomicAdd(&Sarr[row], Sr[k]);
            atomicAdd(&Larr[row], Mr[k] * LN2);
        }
    }
}

// Kernel 2 (merged ctrl+scale, unchanged): per row H = log(S) - L/S,
// cs = sigmoid(-(H - target)/T); write scaled features + control signal.
__global__ __launch_bounds__(256) void k_finish(const float* __restrict__ x,
                                                const float* __restrict__ Sarr,
                                                const float* __restrict__ Larr,
                                                const float* __restrict__ target,
                                                const float* __restrict__ temp,
                                                float* __restrict__ out) {
    const int gid = blockIdx.x * 256 + threadIdx.x;  // float4 index
    const int row = gid >> 6;                        // 64 float4 per row
    float S = Sarr[row], L = Larr[row];
    float H = __logf(S) - L / S;
    float z = (H - target[0]) / temp[0];
    float cs = 1.0f / (1.0f + __expf(z));
    float4 v = ((const float4*)x)[gid];
    float4 o;
    o.x = v.x * cs; o.y = v.y * cs; o.z = v.z * cs; o.w = v.w * cs;
    ((float4*)out)[gid] = o;
    if ((gid & 63) == 0) out[(size_t)N * D + row] = cs;  // control_signal section
}

extern "C" void kernel_launch(void* const* d_in, const int* in_sizes, int n_in,
                              void* d_out, int out_size, void* d_ws, size_t ws_size,
                              hipStream_t stream) {
    const float* x = (const float*)d_in[0];       // features [4,2048,256]
    const float* target = (const float*)d_in[7];  // target_entropy [1]
    const float* temp = (const float*)d_in[8];    // temperature [1]
    float* out = (float*)d_out;

    float* wsf = (float*)d_ws;
    float* sq = wsf;
    float* Sarr = wsf + N;
    float* Larr = wsf + 2 * N;

    // fragment-major bf16 copy of X: in ws if it fits, else park in d_out's
    // first 4 MB (k_finish only writes d_out after k_gram has consumed xb2)
    const size_t need = 3 * (size_t)N * sizeof(float) + (size_t)N * D * sizeof(unsigned short);
    unsigned short* xb2 = (ws_size >= need) ? (unsigned short*)(wsf + 3 * N)
                                            : (unsigned short*)d_out;

    k_cvt<<<N / 16, 64, 0, stream>>>(x, xb2, sq, Sarr, Larr);
    k_gram<<<dim3(32, 16), 256, 0, stream>>>(xb2, sq, temp, Sarr, Larr);
    k_finish<<<(N * (D / 4)) / 256, 256, 0, stream>>>(x, Sarr, Larr, target, temp, out);
}

// Round 4
// 107.257 us; speedup vs baseline: 1.1498x; 1.1498x over previous
//
#include <hip/hip_runtime.h>

#define N 8192
#define D 256

typedef short short8 __attribute__((ext_vector_type(8)));
typedef float f32x4 __attribute__((ext_vector_type(4)));

__device__ __forceinline__ unsigned short f2bf(float f) {
    unsigned int u = __float_as_uint(f);
    u += 0x7fffu + ((u >> 16) & 1u);   // RNE
    return (unsigned short)(u >> 16);
}
__device__ __forceinline__ float bf2f(unsigned short h) {
    return __uint_as_float(((unsigned int)h) << 16);
}

// Kernel 0 (R15 version, unchanged): fp32 -> bf16 into FRAGMENT-MAJOR xb2:
// 16B chunk ((row>>4)*8 + kk)*64 + lane holds
// X[(row>>4)*16 + (lane&15)][kk*32 + (lane>>4)*8 .. +8) as bf16.
// One wave per 16-row group, grid 512 x 64 -> all 256 CUs active.
// Also row squared norms + zero S/L accumulators.
__global__ __launch_bounds__(64) void k_cvt(const float* __restrict__ x,
                                            unsigned short* __restrict__ xb2,
                                            float* __restrict__ sq,
                                            float* __restrict__ Sarr,
                                            float* __restrict__ Larr) {
    const int lane = threadIdx.x & 63;
    const int c = lane & 15, q8 = lane >> 4;
    const int grp = blockIdx.x;               // 16-row group
    const int row = grp * 16 + c;

    float ssum = 0.0f;
#pragma unroll
    for (int kk = 0; kk < 8; ++kk) {
        const float4* gp = (const float4*)(x + (size_t)row * D + kk * 32 + q8 * 8);
        float4 v0 = gp[0], v1 = gp[1];
        unsigned short h[8];
        h[0] = f2bf(v0.x); h[1] = f2bf(v0.y); h[2] = f2bf(v0.z); h[3] = f2bf(v0.w);
        h[4] = f2bf(v1.x); h[5] = f2bf(v1.y); h[6] = f2bf(v1.z); h[7] = f2bf(v1.w);
        short8 p;
#pragma unroll
        for (int i = 0; i < 8; ++i) {
            float f = bf2f(h[i]);
            ssum = fmaf(f, f, ssum);
            p[i] = (short)h[i];
        }
        ((short8*)xb2)[(grp * 8 + kk) * 64 + lane] = p;
    }
    ssum += __shfl_xor(ssum, 16, 64);
    ssum += __shfl_xor(ssum, 32, 64);
    if (q8 == 0) {
        sq[row] = ssum;
        Sarr[row] = 0.0f;
        Larr[row] = 0.0f;
    }
}

// load one 16-col fragment group (8 x 1KB wave-coalesced dwordx4) into regs
__device__ __forceinline__ void ld_b(const short8* __restrict__ xb8, int grp,
                                     int lane, short8 (&bv)[8]) {
#pragma unroll
    for (int kk = 0; kk < 8; ++kk)
        bv[kk] = xb8[(size_t)grp * 512 + kk * 64 + lane];
}

// compute one 256x16 subtile column: 32 MFMA + screened exp2 epilogue.
// Identical math/layout to the verified R13/R16/R17 kernels.
__device__ __forceinline__ void ct_compute(const short8 (&av)[4][8],
                                           const short8 (&bv)[8],
                                           float bc, const float (&ar)[16],
                                           float armax, float c2,
                                           float (&Sr)[16], float (&Mr)[16]) {
    f32x4 acc[4];
#pragma unroll
    for (int tr = 0; tr < 4; ++tr)
#pragma unroll
        for (int r = 0; r < 4; ++r) acc[tr][r] = 0.0f;

#pragma unroll
    for (int kk = 0; kk < 8; ++kk)
#pragma unroll
        for (int tr = 0; tr < 4; ++tr)
            acc[tr] = __builtin_amdgcn_mfma_f32_16x16x32_bf16(
                av[tr][kk], bv[kk], acc[tr], 0, 0, 0);

    // screen: conservative upper bound on t2 over this lane's 16 elems
    float gmax = acc[0][0];
#pragma unroll
    for (int tr = 0; tr < 4; ++tr)
#pragma unroll
        for (int r = 0; r < 4; ++r) gmax = fmaxf(gmax, acc[tr][r]);
    const float bound = fmaf(gmax, c2, armax + bc);

    if (__any(bound >= -115.0f)) {
        // exact slow path (diagonal-touching subtiles, ~1%)
#pragma unroll
        for (int tr = 0; tr < 4; ++tr)
#pragma unroll
            for (int r = 0; r < 4; ++r) {
                float g = acc[tr][r];
                float t2 = fminf(fmaf(g, c2, ar[tr * 4 + r] + bc), 0.0f);
                float e = __builtin_amdgcn_exp2f(t2);
                Sr[tr * 4 + r] += e;
                Mr[tr * 4 + r] = fmaf(e, t2, Mr[tr * 4 + r]);
            }
    }
    // else: all values underflow fp32 -> contribute exactly 0
}

// Kernel 1 (R18: direct-L2 B-path + REGISTER DOUBLE-BUFFER prefetch).
// R17 counters (MfmaUtil 27%, VALU 12.6%, hbm 5.6%, occ 17.5%) showed the
// direct-L2 structure is latency-bound: each ct iteration's 32 MFMAs
// depend on the 8 loads just issued, and at 2 waves/SIMD there is no ILP
// to hide the ~600-900 cyc cross-XCD L2/L3 hit. Fix: classic depth-1
// software pipeline — statically-named bvA/bvB (rule #20), ct loop
// stepped by 2: issue loads for ct+1, MFMA on ct, issue loads for ct+2,
// MFMA on ct+1. The per-tile sq scalar is prefetched the same way.
// A-fragments, screen, C/D mapping, reduction, atomics unchanged.
__global__ __launch_bounds__(256, 2) void k_gram(const unsigned short* __restrict__ xb2,
                                                 const float* __restrict__ sq,
                                                 const float* __restrict__ temp,
                                                 float* __restrict__ Sarr,
                                                 float* __restrict__ Larr) {
    const int tid = threadIdx.x;
    const int wv = tid >> 6, lane = tid & 63;
    const int q8 = lane >> 4, c = lane & 15;
    const int rowbase = blockIdx.x * 256;
    const int ybase = blockIdx.y * 512;
    const float T = temp[0];
    const float LOG2E = 1.44269504f;
    const float s2 = -LOG2E / (2.0f * T * T);   // log2-scaled; t2 = c2*g + ar + bc
    const float c2 = -2.0f * s2;

    // A fragments: wave wv owns rows rowbase + wv*64 .. +63 (coalesced)
    short8 av[4][8];
#pragma unroll
    for (int tr = 0; tr < 4; ++tr) {
        const int grp = (rowbase >> 4) + wv * 4 + tr;
#pragma unroll
        for (int kk = 0; kk < 8; ++kk)
            av[tr][kk] = ((const short8*)xb2)[(grp * 8 + kk) * 64 + lane];
    }
    float ar[16];   // sq[row] * s2 (negative)
#pragma unroll
    for (int tr = 0; tr < 4; ++tr)
#pragma unroll
        for (int r = 0; r < 4; ++r)
            ar[tr * 4 + r] = sq[rowbase + wv * 64 + tr * 16 + q8 * 4 + r] * s2;
    float armax = ar[0];
#pragma unroll
    for (int k = 1; k < 16; ++k) armax = fmaxf(armax, ar[k]);

    float Sr[16], Mr[16];
#pragma unroll
    for (int k = 0; k < 16; ++k) { Sr[k] = 0.f; Mr[k] = 0.f; }

    const short8* xb8 = (const short8*)xb2;
    const int gbase = ybase >> 4;

    // depth-1 pipeline: prologue loads ct=0
    short8 bvA[8], bvB[8];
    float bcA, bcB;
    ld_b(xb8, gbase, lane, bvA);
    bcA = sq[ybase + c] * s2;

    for (int ct = 0; ct < 32; ct += 2) {
        // prefetch ct+1 while computing ct
        ld_b(xb8, gbase + ct + 1, lane, bvB);
        bcB = sq[ybase + (ct + 1) * 16 + c] * s2;

        ct_compute(av, bvA, bcA, ar, armax, c2, Sr, Mr);

        // prefetch ct+2 while computing ct+1 (tail: harmless refetch of 0)
        const int nx = (ct + 2 < 32) ? ct + 2 : 0;
        ld_b(xb8, gbase + nx, lane, bvA);
        bcA = sq[ybase + nx * 16 + c] * s2;

        ct_compute(av, bvB, bcB, ar, armax, c2, Sr, Mr);
    }

    // row-sum commit: reduce across the 16 col-lanes (lane bits 0..3)
#pragma unroll
    for (int m = 1; m <= 8; m <<= 1)
#pragma unroll
        for (int k = 0; k < 16; ++k) {
            Sr[k] += __shfl_xor(Sr[k], m, 64);
            Mr[k] += __shfl_xor(Mr[k], m, 64);
        }
    if (c == 0) {
        const float LN2 = 0.69314718f;   // Mr holds sum e*log2(k); rescale to ln
#pragma unroll
        for (int k = 0; k < 16; ++k) {
            int row = rowbase + wv * 64 + (k >> 2) * 16 + q8 * 4 + (k & 3);
            atomicAdd(&Sarr[row], Sr[k]);
            atomicAdd(&Larr[row], Mr[k] * LN2);
        }
    }
}

// Kernel 2 (merged ctrl+scale, unchanged): per row H = log(S) - L/S,
// cs = sigmoid(-(H - target)/T); write scaled features + control signal.
__global__ __launch_bounds__(256) void k_finish(const float* __restrict__ x,
                                                const float* __restrict__ Sarr,
                                                const float* __restrict__ Larr,
                                                const float* __restrict__ target,
                                                const float* __restrict__ temp,
                                                float* __restrict__ out) {
    const int gid = blockIdx.x * 256 + threadIdx.x;  // float4 index
    const int row = gid >> 6;                        // 64 float4 per row
    float S = Sarr[row], L = Larr[row];
    float H = __logf(S) - L / S;
    float z = (H - target[0]) / temp[0];
    float cs = 1.0f / (1.0f + __expf(z));
    float4 v = ((const float4*)x)[gid];
    float4 o;
    o.x = v.x * cs; o.y = v.y * cs; o.z = v.z * cs; o.w = v.w * cs;
    ((float4*)out)[gid] = o;
    if ((gid & 63) == 0) out[(size_t)N * D + row] = cs;  // control_signal section
}

extern "C" void kernel_launch(void* const* d_in, const int* in_sizes, int n_in,
                              void* d_out, int out_size, void* d_ws, size_t ws_size,
                              hipStream_t stream) {
    const float* x = (const float*)d_in[0];       // features [4,2048,256]
    const float* target = (const float*)d_in[7];  // target_entropy [1]
    const float* temp = (const float*)d_in[8];    // temperature [1]
    float* out = (float*)d_out;

    float* wsf = (float*)d_ws;
    float* sq = wsf;
    float* Sarr = wsf + N;
    float* Larr = wsf + 2 * N;

    // fragment-major bf16 copy of X: in ws if it fits, else park in d_out's
    // first 4 MB (k_finish only writes d_out after k_gram has consumed xb2)
    const size_t need = 3 * (size_t)N * sizeof(float) + (size_t)N * D * sizeof(unsigned short);
    unsigned short* xb2 = (ws_size >= need) ? (unsigned short*)(wsf + 3 * N)
                                            : (unsigned short*)d_out;

    k_cvt<<<N / 16, 64, 0, stream>>>(x, xb2, sq, Sarr, Larr);
    k_gram<<<dim3(32, 16), 256, 0, stream>>>(xb2, sq, temp, Sarr, Larr);
    k_finish<<<(N * (D / 4)) / 256, 256, 0, stream>>>(x, Sarr, Larr, target, temp, out);
}